// Round 17
// baseline (153.035 us; speedup 1.0000x reference)
//
#include <hip/hip_runtime.h>
#include <hip/hip_bf16.h>
#include <stdint.h>

#define S_  2048
#define B_  2
#define H_  16
#define D_  1024
#define HD_ 64

typedef short short8 __attribute__((ext_vector_type(8)));
typedef float f32x4  __attribute__((ext_vector_type(4)));
typedef float f32x16 __attribute__((ext_vector_type(16)));

__device__ __forceinline__ unsigned short bf16_rne(float f) {
  unsigned int u = __float_as_uint(f);
  u += 0x7fffu + ((u >> 16) & 1u);
  return (unsigned short)(u >> 16);
}

__device__ __forceinline__ f32x4 mfma_bf16(short8 a, short8 b, f32x4 c) {
  return __builtin_amdgcn_mfma_f32_16x16x32_bf16(a, b, c, 0, 0, 0);
}

__device__ __forceinline__ f32x16 mfma32(short8 a, short8 b, f32x16 c) {
  return __builtin_amdgcn_mfma_f32_32x32x16_bf16(a, b, c, 0, 0, 0);
}

__device__ __forceinline__ unsigned int cvtpk_bf16(float lo, float hi) {
  unsigned int r;
  asm("v_cvt_pk_bf16_f32 %0, %1, %2" : "=v"(r) : "v"(lo), "v"(hi));
  return r;
}

// ---------------- fused f32 -> bf16 for the 3 input tensors ----------------
__global__ void cvt3_kernel(const float* __restrict__ a, unsigned short* __restrict__ oa, int na8,
                            const float* __restrict__ b, unsigned short* __restrict__ ob, int nb8,
                            const float* __restrict__ c, unsigned short* __restrict__ oc, int nc8) {
  int i = blockIdx.x * blockDim.x + threadIdx.x;
  const float* in; unsigned short* out; int idx;
  if (i < na8) { in = a; out = oa; idx = i; }
  else if (i < na8 + nb8) { in = b; out = ob; idx = i - na8; }
  else if (i < na8 + nb8 + nc8) { in = c; out = oc; idx = i - na8 - nb8; }
  else return;
  const float4* p = (const float4*)in + (size_t)idx * 2;
  float4 x = p[0], y = p[1];
  union { unsigned short u[8]; short8 v; } r;
  r.u[0] = bf16_rne(x.x); r.u[1] = bf16_rne(x.y);
  r.u[2] = bf16_rne(x.z); r.u[3] = bf16_rne(x.w);
  r.u[4] = bf16_rne(y.x); r.u[5] = bf16_rne(y.y);
  r.u[6] = bf16_rne(y.z); r.u[7] = bf16_rne(y.w);
  *((short8*)out + idx) = r.v;
}

// ---------------- per-batch valid length from padding mask ----------------
__global__ void lengths_kernel(const void* __restrict__ mask, int* __restrict__ lens) {
  __shared__ int mn[B_];
  __shared__ int anyb;
  int t = threadIdx.x;
  if (t < B_) mn[t] = S_;
  if (t == 0) anyb = 0;
  __syncthreads();
  const unsigned char* mb = (const unsigned char*)mask;
  for (int i = t; i < B_ * S_; i += 256) {
    if (mb[i]) { anyb = 1; atomicMin(&mn[i >> 11], i & (S_ - 1)); }
  }
  __syncthreads();
  if (!anyb) {
    const int* mi = (const int*)mask;
    for (int i = t; i < B_ * S_; i += 256) {
      if (mi[i]) atomicMin(&mn[i >> 11], i & (S_ - 1));
    }
    __syncthreads();
  }
  if (t < B_) lens[t] = mn[t];
}

// ---------------- 256x256 8-phase bf16 GEMM (QKV, scatter epilogue) --------
// Q scaled by 0.125*log2e (exp2-base softmax); K, V written to [bh][s][64].
__global__ __launch_bounds__(512, 2) void gemm8p_kernel(
    const unsigned short* __restrict__ A,
    const unsigned short* __restrict__ W,
    int K, int NBX,
    const float* __restrict__ bias,
    unsigned short* __restrict__ qb,
    unsigned short* __restrict__ kb,
    unsigned short* __restrict__ vb) {
  __shared__ __align__(16) unsigned short lds[65536];   // 128 KB

  const int nwg = gridDim.x;
  const int cpx = nwg >> 3;
  const int bid = blockIdx.x;
  const int virt = (bid & 7) * cpx + (bid >> 3);
  const int bx = virt % NBX, by = virt / NBX;
  const int tile_m = by * 256, tile_n = bx * 256;
  const int t = threadIdx.x;
  const int lane = t & 63, w = t >> 6;
  const int wm = w >> 2, wn = w & 3;
  const int l15 = lane & 15, lk = lane >> 4;
  const int NT = K >> 6;

  f32x4 acc[8][4];
#pragma unroll
  for (int i = 0; i < 8; i++)
#pragma unroll
    for (int j = 0; j < 4; j++) { f32x4 z = {0.f, 0.f, 0.f, 0.f}; acc[i][j] = z; }

  const int L0 = t, L1 = 512 + t;
  const int r0 = L0 >> 3, c0 = (L0 & 7) ^ (r0 & 7);
  const int r1 = L1 >> 3, c1 = (L1 & 7) ^ (r1 & 7);

#define STAGE_HALF(SRC, GROW0, DSTE, KC)                                      \
  {                                                                           \
    __builtin_amdgcn_global_load_lds(                                         \
        (const __attribute__((address_space(1))) void*)(                      \
            (SRC) + (size_t)((GROW0) + r0) * K + (KC) + c0 * 8),              \
        (__attribute__((address_space(3))) void*)(&lds[(DSTE) + L0 * 8]),     \
        16, 0, 0);                                                            \
    __builtin_amdgcn_global_load_lds(                                         \
        (const __attribute__((address_space(1))) void*)(                      \
            (SRC) + (size_t)((GROW0) + r1) * K + (KC) + c1 * 8),              \
        (__attribute__((address_space(3))) void*)(&lds[(DSTE) + L1 * 8]),     \
        16, 0, 0);                                                            \
  }

  STAGE_HALF(A, tile_m,        0,    0);
  STAGE_HALF(W, tile_n,        32768, 0);
  STAGE_HALF(A, tile_m + 128,  8192, 0);
  STAGE_HALF(W, tile_n + 128,  32768 + 8192, 0);
  asm volatile("s_waitcnt vmcnt(4)" ::: "memory");
  __builtin_amdgcn_s_barrier();

  for (int tc = 0; tc < NT; ++tc) {
    const int cb = (tc & 1) * 16384;
    const int ob = ((tc & 1) ^ 1) * 16384;
    int tn = tc + 1; if (tn >= NT) tn = NT - 1;
    const int k0n = tn << 6;

#pragma unroll
    for (int p = 0; p < 4; ++p) {
      const int mh = (p & 1);
      const int nh = (p >> 1);
      short8 af[4][2], bfr[2][2];
#pragma unroll
      for (int fi = 0; fi < 4; ++fi) {
        const int rl = fi * 32 + wm * 16 + l15;
#pragma unroll
        for (int ks = 0; ks < 2; ++ks) {
          const int sw = (ks * 4 + lk) ^ (rl & 7);
          af[fi][ks] = *(const short8*)&lds[cb + mh * 8192 + rl * 64 + sw * 8];
        }
      }
#pragma unroll
      for (int fj = 0; fj < 2; ++fj) {
        const int cl = wn * 32 + fj * 16 + l15;
#pragma unroll
        for (int ks = 0; ks < 2; ++ks) {
          const int sw = (ks * 4 + lk) ^ (cl & 7);
          bfr[fj][ks] =
              *(const short8*)&lds[32768 + cb + nh * 8192 + cl * 64 + sw * 8];
        }
      }
      if (p == 0)      STAGE_HALF(A, tile_m,       ob,                k0n)
      else if (p == 1) STAGE_HALF(W, tile_n,       32768 + ob,        k0n)
      else if (p == 2) STAGE_HALF(A, tile_m + 128, ob + 8192,         k0n)
      else             STAGE_HALF(W, tile_n + 128, 32768 + ob + 8192, k0n);
      if (p != 2) asm volatile("s_waitcnt vmcnt(4)" ::: "memory");
      else        asm volatile("" ::: "memory");
      __builtin_amdgcn_s_barrier();
      asm volatile("s_waitcnt lgkmcnt(0)" ::: "memory");
      __builtin_amdgcn_s_setprio(1);
#pragma unroll
      for (int fi = 0; fi < 4; ++fi)
#pragma unroll
        for (int fj = 0; fj < 2; ++fj)
#pragma unroll
          for (int ks = 0; ks < 2; ++ks)
            acc[mh * 4 + fi][nh * 2 + fj] =
                mfma_bf16(af[fi][ks], bfr[fj][ks], acc[mh * 4 + fi][nh * 2 + fj]);
      __builtin_amdgcn_s_setprio(0);
      __builtin_amdgcn_s_barrier();
    }
  }
  asm volatile("s_waitcnt vmcnt(0)" ::: "memory");
#undef STAGE_HALF

#pragma unroll
  for (int j = 0; j < 4; ++j) {
    const int gn = tile_n + (j >> 1) * 128 + wn * 32 + (j & 1) * 16 + l15;
    const float bv = bias[gn];
    const int which = gn >> 10, dd = gn & (D_ - 1);
    const int h = dd >> 6, d = dd & 63;
    unsigned short* dstp = (which == 0) ? qb : (which == 1) ? kb : vb;
    const float mul = (which == 0) ? 0.18033688011112042f : 1.0f; // 0.125*log2e
#pragma unroll
    for (int i = 0; i < 8; ++i) {
      const int gmb = tile_m + (i >> 2) * 128 + (i & 3) * 32 + wm * 16 + lk * 4;
#pragma unroll
      for (int r = 0; r < 4; ++r) {
        const int gm = gmb + r;
        const int bb = gm >> 11, s = gm & (S_ - 1);
        dstp[((size_t)((bb * H_ + h) * S_ + s)) * HD_ + d] =
            bf16_rne((acc[i][j][r] + bv) * mul);
      }
    }
  }
}

// ---------------- 128x128 bf16 GEMM, C = A * W^T + bias (f32 out) ----------
__global__ __launch_bounds__(256) void gemm_bt_kernel(
    const unsigned short* __restrict__ A,
    const unsigned short* __restrict__ W,
    int K, int N,
    const float* __restrict__ bias,
    float* __restrict__ outf) {
  __shared__ unsigned short As[128 * 32];
  __shared__ unsigned short Bs[128 * 32];
  const int tile_m = blockIdx.y * 128;
  const int tile_n = blockIdx.x * 128;
  const int t = threadIdx.x;
  const int lane = t & 63;
  const int w = t >> 6;
  const int wr = w >> 1, wc = w & 1;
  const int l15 = lane & 15, lk = lane >> 4;

  f32x4 acc[4][4];
#pragma unroll
  for (int i = 0; i < 4; i++)
#pragma unroll
    for (int j = 0; j < 4; j++) { f32x4 z = {0.f, 0.f, 0.f, 0.f}; acc[i][j] = z; }

  for (int k0 = 0; k0 < K; k0 += 32) {
#pragma unroll
    for (int c = 0; c < 2; ++c) {
      int e = (c * 256 + t) * 8;
      int row = e >> 5, col = e & 31;
      __builtin_amdgcn_global_load_lds(
          (__attribute__((address_space(1))) void*)(A + (size_t)(tile_m + row) * K + k0 + col),
          (__attribute__((address_space(3))) void*)(&As[e]), 16, 0, 0);
      __builtin_amdgcn_global_load_lds(
          (__attribute__((address_space(1))) void*)(W + (size_t)(tile_n + row) * K + k0 + col),
          (__attribute__((address_space(3))) void*)(&Bs[e]), 16, 0, 0);
    }
    asm volatile("s_waitcnt vmcnt(0)" ::: "memory");
    __syncthreads();

    short8 af[4], bfr[4];
#pragma unroll
    for (int i = 0; i < 4; i++)
      af[i] = *(const short8*)&As[(wr * 64 + i * 16 + l15) * 32 + lk * 8];
#pragma unroll
    for (int j = 0; j < 4; j++)
      bfr[j] = *(const short8*)&Bs[(wc * 64 + j * 16 + l15) * 32 + lk * 8];
#pragma unroll
    for (int i = 0; i < 4; i++)
#pragma unroll
      for (int j = 0; j < 4; j++)
        acc[i][j] = mfma_bf16(af[i], bfr[j], acc[i][j]);
    __syncthreads();
  }

#pragma unroll
  for (int i = 0; i < 4; i++) {
#pragma unroll
    for (int j = 0; j < 4; j++) {
      int gn = tile_n + wc * 64 + j * 16 + l15;
      float bv = bias[gn];
#pragma unroll
      for (int r = 0; r < 4; r++) {
        int gm = tile_m + wr * 64 + i * 16 + lk * 4 + r;
        outf[(size_t)gm * N + gn] = acc[i][j][r] + bv;
      }
    }
  }
}

// ---------------- flash attention: chunked block-level split-K ------------
// R13-verified 64-row/4-wave/2-group body. Block = (bh, qt, chunk of <=8
// key tiles); 2560 blocks -> 10/CU (4 resident, 6 queued: continuous
// refill, <=4 rounds/block). Fixed-base exp2 softmax makes cross-block
// merge a plain sum: qt<=7 (single chunk) writes normalized bf16 directly;
// qt>=8 chunks atomicAdd un-normalized (o,l) f32 partials (oacc = d_out
// reused as scratch; lacc in dead wqkv region); attn_merge normalizes.
__global__ __launch_bounds__(256, 3) void attn_kernel(
    const unsigned short* __restrict__ qbuf,
    const unsigned short* __restrict__ kbuf,
    const unsigned short* __restrict__ vbuf,
    const int* __restrict__ lens,
    unsigned short* __restrict__ attn_out,
    float* __restrict__ oacc,
    float* __restrict__ lacc) {
  __shared__ __align__(16) char smem[33792];
  __shared__ float lsh[2][64];
  // Ks[g] u16[64][64] XOR-swz @ g*8192 ; Vt[g] u32[64][34] @ 16384+g*8704
  // epilogue overlay: mo f32[64][66] @ 0

  const int bid = blockIdx.x;
  const int xcd = bid & 7, idx = bid >> 3;       // idx 0..319
  const int bh = (xcd << 2) | (idx & 3);         // 4 heads per XCD
  const int cid = idx >> 2;                      // chunk id 0..79
  const int m = (cid < 8) ? 0 : (cid < 24) ? 1 : (cid < 48) ? 2 : 3;
  const int cbase = 4 * m * (m + 1);
  const int qt = 8 * m + (cid - cbase) / (m + 1);
  const int chunk = (cid - cbase) % (m + 1);
  const int nch = m + 1;                         // chunks for this qt
  const int b = bh >> 4;
  const int len = lens[b];
  const int t = threadIdx.x;
  const int lane = t & 63, w = t >> 6;
  const int g = w >> 1, wq = w & 1;
  const int l31 = lane & 31, hi = lane >> 5;
  const int hi8 = hi * 8, hi4 = hi * 4;
  const int q0 = qt * 64 + wq * 32;
  const int qme = q0 + l31;

  unsigned short* Ks = (unsigned short*)(smem + g * 8192);
  unsigned int*   Vt = (unsigned int*)(smem + 16384 + g * 8704);

  const unsigned short* qbh = qbuf + (size_t)bh * S_ * HD_;
  const unsigned short* kbh = kbuf + (size_t)bh * S_ * HD_;
  const unsigned short* vbh = vbuf + (size_t)bh * S_ * HD_;

  short8 qf[4];
#pragma unroll
  for (int ds = 0; ds < 4; ++ds)
    qf[ds] = *(const short8*)&qbh[(size_t)(q0 + l31) * HD_ + ds * 16 + hi8];

  f32x16 o[2] = {{}, {}};
  float rsum = 0.f;

  const int ke = (len - 1) >> 6;
  const int kt_end = qt < ke ? qt : ke;          // len==0 -> negative
  const int k0t = chunk * 8;
  const int klast = (k0t + 7 < kt_end) ? (k0t + 7) : kt_end;  // may be < k0t
  const int count = klast - k0t + 1;             // may be <= 0
  const int NI = (count + 1) >> 1;               // <=0 -> loop skipped

  // staging decomposition within a 128-thread group
  const int tg = t & 127;
  const int kr0 = tg >> 3, kc0 = tg & 7;         // K: 4 rows kr0+16m
  const int vr2 = tg & 31, vcb = (tg >> 5) << 1; // V: key-pair, 2 d-groups

  short8 pk[4], pva0 = {}, pva1 = {}, pvb0 = {}, pvb1 = {};
#pragma unroll
  for (int mm = 0; mm < 4; ++mm) pk[mm] = pva0;

#define LDG(KT)                                                               \
  {                                                                           \
    int ks_ = (KT) * 64;                                                      \
    pk[0] = *(const short8*)&kbh[(size_t)(ks_ + kr0     ) * HD_ + kc0 * 8];   \
    pk[1] = *(const short8*)&kbh[(size_t)(ks_ + kr0 + 16) * HD_ + kc0 * 8];   \
    pk[2] = *(const short8*)&kbh[(size_t)(ks_ + kr0 + 32) * HD_ + kc0 * 8];   \
    pk[3] = *(const short8*)&kbh[(size_t)(ks_ + kr0 + 48) * HD_ + kc0 * 8];   \
    const unsigned short* vp = vbh + (size_t)(ks_ + 2 * vr2) * HD_ + vcb * 8; \
    pva0 = *(const short8*)vp;       pva1 = *(const short8*)(vp + HD_);       \
    pvb0 = *(const short8*)(vp + 8); pvb1 = *(const short8*)(vp + HD_ + 8);   \
  }

  int my_kt = k0t + g;
  bool act = (my_kt <= klast);
  if (act) LDG(my_kt);

  typedef union { unsigned int u[4]; short8 s; } pa_t;

  for (int i = 0; i < NI; ++i) {
    __syncthreads();
    if (act) {
#pragma unroll
      for (int mm = 0; mm < 4; ++mm) {
        const int r = kr0 + 16 * mm;
        *(short8*)&Ks[r * 64 + ((kc0 ^ (r & 7)) << 3)] = pk[mm];
      }
#pragma unroll
      for (int j = 0; j < 8; ++j) {
        unsigned int w0 = (unsigned int)(unsigned short)pva0[j] |
                          ((unsigned int)(unsigned short)pva1[j] << 16);
        unsigned int w1 = (unsigned int)(unsigned short)pvb0[j] |
                          ((unsigned int)(unsigned short)pvb1[j] << 16);
        Vt[(vcb * 8 + j) * 34 + vr2] = w0;
        Vt[((vcb + 1) * 8 + j) * 34 + vr2] = w1;
      }
    }
    __syncthreads();
    const int nxt = my_kt + 2;
    const bool nact = (nxt <= klast);
    if (nact) LDG(nxt);

    const int ks0 = my_kt * 64;
    if (act && ks0 <= q0 + 31) {
      // mask needed iff tile touches the diagonal (last key >= first q-row)
      // or the padding boundary. NOTE: >= q0, not > q0+31 (wq=1 diag tile!)
      const bool needM = (ks0 + 63 >= q0) || (ks0 + 63 >= len);
      const bool dokb1 = (ks0 + 32 <= q0 + 31) && (ks0 + 32 < len);

      pa_t pa[4];
      // ---- kb = 0 ----
      {
        f32x16 s0 = {};
#pragma unroll
        for (int ds = 0; ds < 4; ++ds) {
          const int cg = ((ds << 1) | hi) ^ (l31 & 7);
          const short8 kf = *(const short8*)&Ks[l31 * 64 + (cg << 3)];
          s0 = mfma32(kf, qf[ds], s0);
        }
        float pr[16];
#pragma unroll
        for (int r = 0; r < 16; ++r) {
          const int crow = (r & 3) + 8 * (r >> 2) + hi4;
          float p = exp2f(s0[r]);
          if (needM) {
            const int key = ks0 + crow;
            if (key > qme || key >= len) p = 0.f;
          }
          pr[r] = p; rsum += p;
        }
        unsigned int A0 = cvtpk_bf16(pr[0], pr[1]);
        unsigned int A1 = cvtpk_bf16(pr[2], pr[3]);
        unsigned int B0 = cvtpk_bf16(pr[4], pr[5]);
        unsigned int B1 = cvtpk_bf16(pr[6], pr[7]);
        asm volatile("v_permlane32_swap_b32 %0, %1" : "+v"(A0), "+v"(B0));
        asm volatile("v_permlane32_swap_b32 %0, %1" : "+v"(A1), "+v"(B1));
        pa[0].u[0] = A0; pa[0].u[1] = A1; pa[0].u[2] = B0; pa[0].u[3] = B1;
        unsigned int C0 = cvtpk_bf16(pr[8], pr[9]);
        unsigned int C1 = cvtpk_bf16(pr[10], pr[11]);
        unsigned int D0 = cvtpk_bf16(pr[12], pr[13]);
        unsigned int D1 = cvtpk_bf16(pr[14], pr[15]);
        asm volatile("v_permlane32_swap_b32 %0, %1" : "+v"(C0), "+v"(D0));
        asm volatile("v_permlane32_swap_b32 %0, %1" : "+v"(C1), "+v"(D1));
        pa[1].u[0] = C0; pa[1].u[1] = C1; pa[1].u[2] = D0; pa[1].u[3] = D1;
      }
      // ---- kb = 1 ----
      if (dokb1) {
        f32x16 s1 = {};
#pragma unroll
        for (int ds = 0; ds < 4; ++ds) {
          const int cg = ((ds << 1) | hi) ^ (l31 & 7);
          const short8 kf = *(const short8*)&Ks[(32 + l31) * 64 + (cg << 3)];
          s1 = mfma32(kf, qf[ds], s1);
        }
        float pr[16];
#pragma unroll
        for (int r = 0; r < 16; ++r) {
          const int crow = 32 + (r & 3) + 8 * (r >> 2) + hi4;
          float p = exp2f(s1[r]);
          if (needM) {
            const int key = ks0 + crow;
            if (key > qme || key >= len) p = 0.f;
          }
          pr[r] = p; rsum += p;
        }
        unsigned int A0 = cvtpk_bf16(pr[0], pr[1]);
        unsigned int A1 = cvtpk_bf16(pr[2], pr[3]);
        unsigned int B0 = cvtpk_bf16(pr[4], pr[5]);
        unsigned int B1 = cvtpk_bf16(pr[6], pr[7]);
        asm volatile("v_permlane32_swap_b32 %0, %1" : "+v"(A0), "+v"(B0));
        asm volatile("v_permlane32_swap_b32 %0, %1" : "+v"(A1), "+v"(B1));
        pa[2].u[0] = A0; pa[2].u[1] = A1; pa[2].u[2] = B0; pa[2].u[3] = B1;
        unsigned int C0 = cvtpk_bf16(pr[8], pr[9]);
        unsigned int C1 = cvtpk_bf16(pr[10], pr[11]);
        unsigned int D0 = cvtpk_bf16(pr[12], pr[13]);
        unsigned int D1 = cvtpk_bf16(pr[14], pr[15]);
        asm volatile("v_permlane32_swap_b32 %0, %1" : "+v"(C0), "+v"(D0));
        asm volatile("v_permlane32_swap_b32 %0, %1" : "+v"(C1), "+v"(D1));
        pa[3].u[0] = C0; pa[3].u[1] = C1; pa[3].u[2] = D0; pa[3].u[3] = D1;
      }
      // ---- PV ----
#pragma unroll
      for (int dh = 0; dh < 2; ++dh) {
        const int vbase = (dh * 32 + l31) * 34 + hi4;
#pragma unroll
        for (int ks = 0; ks < 4; ++ks) {
          if (ks >= 2 && !dokb1) continue;
          uint2 va = *(const uint2*)&Vt[vbase + 8 * ks];
          uint2 vb2 = *(const uint2*)&Vt[vbase + 8 * ks + 2];
          pa_t vv;
          vv.u[0] = va.x; vv.u[1] = va.y; vv.u[2] = vb2.x; vv.u[3] = vb2.y;
          o[dh] = mfma32(pa[ks].s, vv.s, o[dh]);
        }
      }
    }
    my_kt = nxt; act = nact;
  }
#undef LDG

  rsum += __shfl_xor(rsum, 32, 64);

  float* mo = (float*)smem;                       // [64][66]
  __syncthreads();
  if (g == 1) {
#pragma unroll
    for (int r = 0; r < 16; ++r) {
      const int qb = wq * 32 + (r & 3) + 8 * (r >> 2) + hi4;
      mo[qb * 66 + l31]      = o[0][r];
      mo[qb * 66 + 32 + l31] = o[1][r];
    }
    if (hi == 0) lsh[1][wq * 32 + l31] = rsum;
  }
  __syncthreads();
  if (g == 0) {
    const int myrow = wq * 32 + l31;
    const float lt = rsum + lsh[1][myrow];
    if (nch == 1) {
      // single-chunk: write normalized bf16 directly (R13 path)
      const float inv = (lt > 0.f) ? (1.0f / lt) : 0.f;
      if (hi == 0) lsh[0][myrow] = inv;
#pragma unroll
      for (int r = 0; r < 16; ++r) {
        const int cr = (r & 3) + 8 * (r >> 2) + hi4;
        const int qb = wq * 32 + cr;
        const float iv = lsh[0][qb];
        const int s = qt * 64 + qb;
        unsigned short* op =
            &attn_out[((size_t)(b * S_ + s)) * D_ + (bh & 15) * HD_ + l31];
        op[0]  = bf16_rne((o[0][r] + mo[qb * 66 + l31]) * iv);
        op[32] = bf16_rne((o[1][r] + mo[qb * 66 + 32 + l31]) * iv);
      }
    } else {
      // multi-chunk: atomic f32 partial accumulation (un-normalized)
      if (hi == 0) atomicAdd(&lacc[(bh << 11) + qt * 64 + myrow], lt);
#pragma unroll
      for (int r = 0; r < 16; ++r) {
        const int cr = (r & 3) + 8 * (r >> 2) + hi4;
        const int qb = wq * 32 + cr;
        const int s = qt * 64 + qb;
        float* oa = &oacc[((size_t)(b * S_ + s)) * D_ + (bh & 15) * HD_ + l31];
        atomicAdd(oa,      o[0][r] + mo[qb * 66 + l31]);
        atomicAdd(oa + 32, o[1][r] + mo[qb * 66 + 32 + l31]);
      }
    }
  }
}

// ---------------- normalize multi-chunk rows (s >= 512) -------------------
__global__ __launch_bounds__(256) void attn_merge_kernel(
    const float* __restrict__ oacc, const float* __restrict__ lacc,
    unsigned short* __restrict__ attn_out) {
  const int q = blockIdx.x * 256 + threadIdx.x;   // quad id, 786432 total
  const int b = q / 393216;
  const int rem = q - b * 393216;
  const int s = 512 + (rem >> 8);
  const int hd = rem & 255;
  const int h = hd >> 4, dq = hd & 15;
  const float l = lacc[((b * 16 + h) << 11) + s];
  const float inv = (l > 0.f) ? (1.0f / l) : 0.f;
  const size_t off = ((size_t)(b * S_ + s)) * D_ + h * HD_ + dq * 4;
  const float4 v = *(const float4*)&oacc[off];
  union { unsigned short u[4]; uint2 v2; } r;
  r.u[0] = bf16_rne(v.x * inv); r.u[1] = bf16_rne(v.y * inv);
  r.u[2] = bf16_rne(v.z * inv); r.u[3] = bf16_rne(v.w * inv);
  *(uint2*)&attn_out[off] = r.v2;
}

extern "C" void kernel_launch(void* const* d_in, const int* in_sizes, int n_in,
                              void* d_out, int out_size, void* d_ws, size_t ws_size,
                              hipStream_t stream) {
  const float* query = (const float*)d_in[0];
  const void*  mask  = d_in[1];
  const float* qkv_w = (const float*)d_in[2];
  const float* qkv_b = (const float*)d_in[3];
  const float* out_w = (const float*)d_in[4];
  const float* out_b = (const float*)d_in[5];
  float* out = (float*)d_out;

  char* ws = (char*)d_ws;
  unsigned short* qx     = (unsigned short*)(ws);                    // 0-8M
  unsigned short* wqkv   = (unsigned short*)(ws + (8u  << 20));      // 8-14M
  unsigned short* wout   = (unsigned short*)(ws + (14u << 20));      // 14-16M
  unsigned short* qbuf   = (unsigned short*)(ws + (16u << 20));      // 16-24M
  unsigned short* kbuf   = (unsigned short*)(ws + (24u << 20));      // 24-32M
  unsigned short* vbuf   = (unsigned short*)(ws + (32u << 20));      // 32-40M
  unsigned short* attn_o = qx;                                       // reuse 0-8M
  float* lacc            = (float*)(ws + (8u << 20));                // reuse wqkv (dead after gemm8p)
  float* oacc            = out;                                      // d_out as f32 scratch
  int* lens              = (int*)(ws + (40u << 20));

  lengths_kernel<<<1, 256, 0, stream>>>(mask, lens);
  hipMemsetAsync(d_out, 0, (size_t)B_ * S_ * D_ * 4, stream);
  const int na8 = B_ * S_ * D_ / 8, nb8 = 3 * D_ * D_ / 8, nc8 = D_ * D_ / 8;
  cvt3_kernel<<<(na8 + nb8 + nc8) / 256, 256, 0, stream>>>(
      query, qx, na8, qkv_w, wqkv, nb8, out_w, wout, nc8);

  gemm8p_kernel<<<192, 512, 0, stream>>>(qx, wqkv, D_, 3 * D_ / 256, qkv_b,
                                         qbuf, kbuf, vbuf);

  // zero lacc AFTER gemm8p (it overlays wqkv, which gemm8p reads)
  hipMemsetAsync(lacc, 0, 32 * 2048 * 4, stream);

  attn_kernel<<<2560, 256, 0, stream>>>(qbuf, kbuf, vbuf, lens, attn_o,
                                        oacc, lacc);
  attn_merge_kernel<<<3072, 256, 0, stream>>>(oacc, lacc, attn_o);

  dim3 g2(D_ / 128, B_ * S_ / 128);
  gemm_bt_kernel<<<g2, 256, 0, stream>>>(attn_o, wout, D_, D_, out_b, out);
}

// Round 18
// 138.501 us; speedup vs baseline: 1.1049x; 1.1049x over previous
//
#include <hip/hip_runtime.h>
#include <hip/hip_bf16.h>
#include <stdint.h>

#define S_  2048
#define B_  2
#define H_  16
#define D_  1024
#define HD_ 64

typedef short short8 __attribute__((ext_vector_type(8)));
typedef float f32x4  __attribute__((ext_vector_type(4)));
typedef float f32x16 __attribute__((ext_vector_type(16)));

__device__ __forceinline__ unsigned short bf16_rne(float f) {
  unsigned int u = __float_as_uint(f);
  u += 0x7fffu + ((u >> 16) & 1u);
  return (unsigned short)(u >> 16);
}

__device__ __forceinline__ f32x4 mfma_bf16(short8 a, short8 b, f32x4 c) {
  return __builtin_amdgcn_mfma_f32_16x16x32_bf16(a, b, c, 0, 0, 0);
}

__device__ __forceinline__ f32x16 mfma32(short8 a, short8 b, f32x16 c) {
  return __builtin_amdgcn_mfma_f32_32x32x16_bf16(a, b, c, 0, 0, 0);
}

__device__ __forceinline__ unsigned int cvtpk_bf16(float lo, float hi) {
  unsigned int r;
  asm("v_cvt_pk_bf16_f32 %0, %1, %2" : "=v"(r) : "v"(lo), "v"(hi));
  return r;
}

// ---------------- fused f32 -> bf16 for 3 tensors + lengths scan ----------
// Block 0 additionally derives per-batch valid lengths from the mask.
__global__ void cvt3_kernel(const float* __restrict__ a, unsigned short* __restrict__ oa, int na8,
                            const float* __restrict__ b, unsigned short* __restrict__ ob, int nb8,
                            const float* __restrict__ c, unsigned short* __restrict__ oc, int nc8,
                            const void* __restrict__ mask, int* __restrict__ lens) {
  if (blockIdx.x == 0) {
    __shared__ int mn[B_];
    __shared__ int anyb;
    int tt = threadIdx.x;
    if (tt < B_) mn[tt] = S_;
    if (tt == 0) anyb = 0;
    __syncthreads();
    const unsigned char* mb = (const unsigned char*)mask;
    for (int i = tt; i < B_ * S_; i += 256) {
      if (mb[i]) { anyb = 1; atomicMin(&mn[i >> 11], i & (S_ - 1)); }
    }
    __syncthreads();
    if (!anyb) {
      const int* mi = (const int*)mask;
      for (int i = tt; i < B_ * S_; i += 256) {
        if (mi[i]) atomicMin(&mn[i >> 11], i & (S_ - 1));
      }
      __syncthreads();
    }
    if (tt < B_) lens[tt] = mn[tt];
  }
  int i = blockIdx.x * blockDim.x + threadIdx.x;
  const float* in; unsigned short* out; int idx;
  if (i < na8) { in = a; out = oa; idx = i; }
  else if (i < na8 + nb8) { in = b; out = ob; idx = i - na8; }
  else if (i < na8 + nb8 + nc8) { in = c; out = oc; idx = i - na8 - nb8; }
  else return;
  const float4* p = (const float4*)in + (size_t)idx * 2;
  float4 x = p[0], y = p[1];
  union { unsigned short u[8]; short8 v; } r;
  r.u[0] = bf16_rne(x.x); r.u[1] = bf16_rne(x.y);
  r.u[2] = bf16_rne(x.z); r.u[3] = bf16_rne(x.w);
  r.u[4] = bf16_rne(y.x); r.u[5] = bf16_rne(y.y);
  r.u[6] = bf16_rne(y.z); r.u[7] = bf16_rne(y.w);
  *((short8*)out + idx) = r.v;
}

// ---------------- 256x256 8-phase bf16 GEMM (QKV, scatter epilogue) --------
// Q scaled by 0.125*log2e (exp2-base softmax); K, V written to [bh][s][64].
__global__ __launch_bounds__(512, 2) void gemm8p_kernel(
    const unsigned short* __restrict__ A,
    const unsigned short* __restrict__ W,
    int K, int NBX,
    const float* __restrict__ bias,
    unsigned short* __restrict__ qb,
    unsigned short* __restrict__ kb,
    unsigned short* __restrict__ vb) {
  __shared__ __align__(16) unsigned short lds[65536];   // 128 KB

  const int nwg = gridDim.x;
  const int cpx = nwg >> 3;
  const int bid = blockIdx.x;
  const int virt = (bid & 7) * cpx + (bid >> 3);
  const int bx = virt % NBX, by = virt / NBX;
  const int tile_m = by * 256, tile_n = bx * 256;
  const int t = threadIdx.x;
  const int lane = t & 63, w = t >> 6;
  const int wm = w >> 2, wn = w & 3;
  const int l15 = lane & 15, lk = lane >> 4;
  const int NT = K >> 6;

  f32x4 acc[8][4];
#pragma unroll
  for (int i = 0; i < 8; i++)
#pragma unroll
    for (int j = 0; j < 4; j++) { f32x4 z = {0.f, 0.f, 0.f, 0.f}; acc[i][j] = z; }

  const int L0 = t, L1 = 512 + t;
  const int r0 = L0 >> 3, c0 = (L0 & 7) ^ (r0 & 7);
  const int r1 = L1 >> 3, c1 = (L1 & 7) ^ (r1 & 7);

#define STAGE_HALF(SRC, GROW0, DSTE, KC)                                      \
  {                                                                           \
    __builtin_amdgcn_global_load_lds(                                         \
        (const __attribute__((address_space(1))) void*)(                      \
            (SRC) + (size_t)((GROW0) + r0) * K + (KC) + c0 * 8),              \
        (__attribute__((address_space(3))) void*)(&lds[(DSTE) + L0 * 8]),     \
        16, 0, 0);                                                            \
    __builtin_amdgcn_global_load_lds(                                         \
        (const __attribute__((address_space(1))) void*)(                      \
            (SRC) + (size_t)((GROW0) + r1) * K + (KC) + c1 * 8),              \
        (__attribute__((address_space(3))) void*)(&lds[(DSTE) + L1 * 8]),     \
        16, 0, 0);                                                            \
  }

  STAGE_HALF(A, tile_m,        0,    0);
  STAGE_HALF(W, tile_n,        32768, 0);
  STAGE_HALF(A, tile_m + 128,  8192, 0);
  STAGE_HALF(W, tile_n + 128,  32768 + 8192, 0);
  asm volatile("s_waitcnt vmcnt(4)" ::: "memory");
  __builtin_amdgcn_s_barrier();

  for (int tc = 0; tc < NT; ++tc) {
    const int cb = (tc & 1) * 16384;
    const int ob = ((tc & 1) ^ 1) * 16384;
    int tn = tc + 1; if (tn >= NT) tn = NT - 1;
    const int k0n = tn << 6;

#pragma unroll
    for (int p = 0; p < 4; ++p) {
      const int mh = (p & 1);
      const int nh = (p >> 1);
      short8 af[4][2], bfr[2][2];
#pragma unroll
      for (int fi = 0; fi < 4; ++fi) {
        const int rl = fi * 32 + wm * 16 + l15;
#pragma unroll
        for (int ks = 0; ks < 2; ++ks) {
          const int sw = (ks * 4 + lk) ^ (rl & 7);
          af[fi][ks] = *(const short8*)&lds[cb + mh * 8192 + rl * 64 + sw * 8];
        }
      }
#pragma unroll
      for (int fj = 0; fj < 2; ++fj) {
        const int cl = wn * 32 + fj * 16 + l15;
#pragma unroll
        for (int ks = 0; ks < 2; ++ks) {
          const int sw = (ks * 4 + lk) ^ (cl & 7);
          bfr[fj][ks] =
              *(const short8*)&lds[32768 + cb + nh * 8192 + cl * 64 + sw * 8];
        }
      }
      if (p == 0)      STAGE_HALF(A, tile_m,       ob,                k0n)
      else if (p == 1) STAGE_HALF(W, tile_n,       32768 + ob,        k0n)
      else if (p == 2) STAGE_HALF(A, tile_m + 128, ob + 8192,         k0n)
      else             STAGE_HALF(W, tile_n + 128, 32768 + ob + 8192, k0n);
      if (p != 2) asm volatile("s_waitcnt vmcnt(4)" ::: "memory");
      else        asm volatile("" ::: "memory");
      __builtin_amdgcn_s_barrier();
      asm volatile("s_waitcnt lgkmcnt(0)" ::: "memory");
      __builtin_amdgcn_s_setprio(1);
#pragma unroll
      for (int fi = 0; fi < 4; ++fi)
#pragma unroll
        for (int fj = 0; fj < 2; ++fj)
#pragma unroll
          for (int ks = 0; ks < 2; ++ks)
            acc[mh * 4 + fi][nh * 2 + fj] =
                mfma_bf16(af[fi][ks], bfr[fj][ks], acc[mh * 4 + fi][nh * 2 + fj]);
      __builtin_amdgcn_s_setprio(0);
      __builtin_amdgcn_s_barrier();
    }
  }
  asm volatile("s_waitcnt vmcnt(0)" ::: "memory");
#undef STAGE_HALF

#pragma unroll
  for (int j = 0; j < 4; ++j) {
    const int gn = tile_n + (j >> 1) * 128 + wn * 32 + (j & 1) * 16 + l15;
    const float bv = bias[gn];
    const int which = gn >> 10, dd = gn & (D_ - 1);
    const int h = dd >> 6, d = dd & 63;
    unsigned short* dstp = (which == 0) ? qb : (which == 1) ? kb : vb;
    const float mul = (which == 0) ? 0.18033688011112042f : 1.0f; // 0.125*log2e
#pragma unroll
    for (int i = 0; i < 8; ++i) {
      const int gmb = tile_m + (i >> 2) * 128 + (i & 3) * 32 + wm * 16 + lk * 4;
#pragma unroll
      for (int r = 0; r < 4; ++r) {
        const int gm = gmb + r;
        const int bb = gm >> 11, s = gm & (S_ - 1);
        dstp[((size_t)((bb * H_ + h) * S_ + s)) * HD_ + d] =
            bf16_rne((acc[i][j][r] + bv) * mul);
      }
    }
  }
}

// ---------------- 128x128 bf16 GEMM, 2-phase dbuf, C = A*W^T + bias -------
__global__ __launch_bounds__(256) void gemm_bt_kernel(
    const unsigned short* __restrict__ A,
    const unsigned short* __restrict__ W,
    int K, int N,
    const float* __restrict__ bias,
    float* __restrict__ outf) {
  __shared__ unsigned short As[2][128 * 32];
  __shared__ unsigned short Bs[2][128 * 32];
  const int tile_m = blockIdx.y * 128;
  const int tile_n = blockIdx.x * 128;
  const int t = threadIdx.x;
  const int lane = t & 63;
  const int w = t >> 6;
  const int wr = w >> 1, wc = w & 1;
  const int l15 = lane & 15, lk = lane >> 4;
  const int NT = K >> 5;

  f32x4 acc[4][4];
#pragma unroll
  for (int i = 0; i < 4; i++)
#pragma unroll
    for (int j = 0; j < 4; j++) { f32x4 z = {0.f, 0.f, 0.f, 0.f}; acc[i][j] = z; }

#define STAGE_BT(BUF, KC)                                                     \
  {                                                                           \
    _Pragma("unroll")                                                         \
    for (int c = 0; c < 2; ++c) {                                             \
      int e = (c * 256 + t) * 8;                                              \
      int row = e >> 5, col = e & 31;                                         \
      __builtin_amdgcn_global_load_lds(                                       \
          (const __attribute__((address_space(1))) void*)(                    \
              A + (size_t)(tile_m + row) * K + (KC) + col),                   \
          (__attribute__((address_space(3))) void*)(&As[BUF][e]), 16, 0, 0);  \
      __builtin_amdgcn_global_load_lds(                                       \
          (const __attribute__((address_space(1))) void*)(                    \
              W + (size_t)(tile_n + row) * K + (KC) + col),                   \
          (__attribute__((address_space(3))) void*)(&Bs[BUF][e]), 16, 0, 0);  \
    }                                                                         \
  }

  // prologue: stage tile 0, drain, barrier
  STAGE_BT(0, 0);
  asm volatile("s_waitcnt vmcnt(0)" ::: "memory");
  __syncthreads();

  int cur = 0;
  for (int tc = 0; tc < NT; ++tc) {
    // issue next-tile loads into the other buffer (overlap with compute)
    if (tc + 1 < NT) STAGE_BT(cur ^ 1, (tc + 1) << 5);

    const unsigned short* Ac = As[cur];
    const unsigned short* Bc = Bs[cur];
    short8 af[4], bfr[4];
#pragma unroll
    for (int i = 0; i < 4; i++)
      af[i] = *(const short8*)&Ac[(wr * 64 + i * 16 + l15) * 32 + lk * 8];
#pragma unroll
    for (int j = 0; j < 4; j++)
      bfr[j] = *(const short8*)&Bc[(wc * 64 + j * 16 + l15) * 32 + lk * 8];
    __builtin_amdgcn_s_setprio(1);
#pragma unroll
    for (int i = 0; i < 4; i++)
#pragma unroll
      for (int j = 0; j < 4; j++)
        acc[i][j] = mfma_bf16(af[i], bfr[j], acc[i][j]);
    __builtin_amdgcn_s_setprio(0);

    // next tile staged + all waves done reading cur
    asm volatile("s_waitcnt vmcnt(0)" ::: "memory");
    __syncthreads();
    cur ^= 1;
  }
#undef STAGE_BT

#pragma unroll
  for (int i = 0; i < 4; i++) {
#pragma unroll
    for (int j = 0; j < 4; j++) {
      int gn = tile_n + wc * 64 + j * 16 + l15;
      float bv = bias[gn];
#pragma unroll
      for (int r = 0; r < 4; r++) {
        int gm = tile_m + wr * 64 + i * 16 + lk * 4 + r;
        outf[(size_t)gm * N + gn] = acc[i][j][r] + bv;
      }
    }
  }
}

// ---------------- flash attention: 32x32 MFMA, in-register softmax ---------
// R13-verified kernel (best: attn 56us). 2-way split-K, balanced CU
// mapping (each CU gets qt = {x, 15-x, 16+x, 31-x} on one head), exp2f
// softmax (Q pre-scaled 0.125*log2e in gemm8p; verified R14-R16).
__global__ __launch_bounds__(256, 3) void attn_kernel(
    const unsigned short* __restrict__ qbuf,
    const unsigned short* __restrict__ kbuf,
    const unsigned short* __restrict__ vbuf,
    const int* __restrict__ lens,
    unsigned short* __restrict__ attn_out) {
  __shared__ __align__(16) char smem[33792];
  __shared__ float lsh[2][64];
  // Ks[g] u16[64][64] XOR-swz @ g*8192 ; Vt[g] u32[64][34] @ 16384+g*8704
  // epilogue overlay: mo f32[64][66] @ 0

  const int bid = blockIdx.x;
  const int xcd = bid & 7, nn = bid >> 3;
  const int rr = nn >> 5, cc = nn & 31;
  const int bh = (xcd << 2) | (cc & 3);
  const int qlo = cc >> 2;
  const int qt = (rr & 1) ? (8 * rr + 7 - qlo) : (8 * rr + qlo);
  const int b = bh >> 4;
  const int len = lens[b];
  const int t = threadIdx.x;
  const int lane = t & 63, w = t >> 6;
  const int g = w >> 1, wq = w & 1;
  const int l31 = lane & 31, hi = lane >> 5;
  const int hi8 = hi * 8, hi4 = hi * 4;
  const int q0 = qt * 64 + wq * 32;
  const int qme = q0 + l31;

  unsigned short* Ks = (unsigned short*)(smem + g * 8192);
  unsigned int*   Vt = (unsigned int*)(smem + 16384 + g * 8704);

  const unsigned short* qbh = qbuf + (size_t)bh * S_ * HD_;
  const unsigned short* kbh = kbuf + (size_t)bh * S_ * HD_;
  const unsigned short* vbh = vbuf + (size_t)bh * S_ * HD_;

  short8 qf[4];
#pragma unroll
  for (int ds = 0; ds < 4; ++ds)
    qf[ds] = *(const short8*)&qbh[(size_t)(q0 + l31) * HD_ + ds * 16 + hi8];

  f32x16 o[2] = {{}, {}};
  float rsum = 0.f;

  const int ke = (len - 1) >> 6;
  const int kt_end = qt < ke ? qt : ke;
  const int NI = (kt_end >> 1) + 1;

  // staging decomposition within a 128-thread group
  const int tg = t & 127;
  const int kr0 = tg >> 3, kc0 = tg & 7;        // K: 4 rows kr0+16m
  const int vr2 = tg & 31, vcb = (tg >> 5) << 1; // V: key-pair, 2 d-groups

  short8 pk[4], pva0 = {}, pva1 = {}, pvb0 = {}, pvb1 = {};
#pragma unroll
  for (int m = 0; m < 4; ++m) pk[m] = pva0;

#define LDG(KT)                                                               \
  {                                                                           \
    int ks_ = (KT) * 64;                                                      \
    pk[0] = *(const short8*)&kbh[(size_t)(ks_ + kr0     ) * HD_ + kc0 * 8];   \
    pk[1] = *(const short8*)&kbh[(size_t)(ks_ + kr0 + 16) * HD_ + kc0 * 8];   \
    pk[2] = *(const short8*)&kbh[(size_t)(ks_ + kr0 + 32) * HD_ + kc0 * 8];   \
    pk[3] = *(const short8*)&kbh[(size_t)(ks_ + kr0 + 48) * HD_ + kc0 * 8];   \
    const unsigned short* vp = vbh + (size_t)(ks_ + 2 * vr2) * HD_ + vcb * 8; \
    pva0 = *(const short8*)vp;       pva1 = *(const short8*)(vp + HD_);       \
    pvb0 = *(const short8*)(vp + 8); pvb1 = *(const short8*)(vp + HD_ + 8);   \
  }

  int my_kt = g;
  bool act = (my_kt <= kt_end);
  if (act) LDG(my_kt);

  typedef union { unsigned int u[4]; short8 s; } pa_t;

  for (int i = 0; i < NI; ++i) {
    __syncthreads();
    if (act) {
#pragma unroll
      for (int m = 0; m < 4; ++m) {
        const int r = kr0 + 16 * m;
        *(short8*)&Ks[r * 64 + ((kc0 ^ (r & 7)) << 3)] = pk[m];
      }
#pragma unroll
      for (int j = 0; j < 8; ++j) {
        unsigned int w0 = (unsigned int)(unsigned short)pva0[j] |
                          ((unsigned int)(unsigned short)pva1[j] << 16);
        unsigned int w1 = (unsigned int)(unsigned short)pvb0[j] |
                          ((unsigned int)(unsigned short)pvb1[j] << 16);
        Vt[(vcb * 8 + j) * 34 + vr2] = w0;
        Vt[((vcb + 1) * 8 + j) * 34 + vr2] = w1;
      }
    }
    __syncthreads();
    const int nxt = my_kt + 2;
    const bool nact = (nxt <= kt_end);
    if (nact) LDG(nxt);

    const int ks0 = my_kt * 64;
    if (act && ks0 <= q0 + 31) {
      // mask needed iff tile touches the diagonal (last key >= first q-row)
      // or the padding boundary. NOTE: >= q0, not > q0+31 (wq=1 diag tile!)
      const bool needM = (ks0 + 63 >= q0) || (ks0 + 63 >= len);
      const bool dokb1 = (ks0 + 32 <= q0 + 31) && (ks0 + 32 < len);

      pa_t pa[4];
      // ---- kb = 0 ----
      {
        f32x16 s0 = {};
#pragma unroll
        for (int ds = 0; ds < 4; ++ds) {
          const int cg = ((ds << 1) | hi) ^ (l31 & 7);
          const short8 kf = *(const short8*)&Ks[l31 * 64 + (cg << 3)];
          s0 = mfma32(kf, qf[ds], s0);
        }
        float pr[16];
#pragma unroll
        for (int r = 0; r < 16; ++r) {
          const int crow = (r & 3) + 8 * (r >> 2) + hi4;
          float p = exp2f(s0[r]);
          if (needM) {
            const int key = ks0 + crow;
            if (key > qme || key >= len) p = 0.f;
          }
          pr[r] = p; rsum += p;
        }
        unsigned int A0 = cvtpk_bf16(pr[0], pr[1]);
        unsigned int A1 = cvtpk_bf16(pr[2], pr[3]);
        unsigned int B0 = cvtpk_bf16(pr[4], pr[5]);
        unsigned int B1 = cvtpk_bf16(pr[6], pr[7]);
        asm volatile("v_permlane32_swap_b32 %0, %1" : "+v"(A0), "+v"(B0));
        asm volatile("v_permlane32_swap_b32 %0, %1" : "+v"(A1), "+v"(B1));
        pa[0].u[0] = A0; pa[0].u[1] = A1; pa[0].u[2] = B0; pa[0].u[3] = B1;
        unsigned int C0 = cvtpk_bf16(pr[8], pr[9]);
        unsigned int C1 = cvtpk_bf16(pr[10], pr[11]);
        unsigned int D0 = cvtpk_bf16(pr[12], pr[13]);
        unsigned int D1 = cvtpk_bf16(pr[14], pr[15]);
        asm volatile("v_permlane32_swap_b32 %0, %1" : "+v"(C0), "+v"(D0));
        asm volatile("v_permlane32_swap_b32 %0, %1" : "+v"(C1), "+v"(D1));
        pa[1].u[0] = C0; pa[1].u[1] = C1; pa[1].u[2] = D0; pa[1].u[3] = D1;
      }
      // ---- kb = 1 ----
      if (dokb1) {
        f32x16 s1 = {};
#pragma unroll
        for (int ds = 0; ds < 4; ++ds) {
          const int cg = ((ds << 1) | hi) ^ (l31 & 7);
          const short8 kf = *(const short8*)&Ks[(32 + l31) * 64 + (cg << 3)];
          s1 = mfma32(kf, qf[ds], s1);
        }
        float pr[16];
#pragma unroll
        for (int r = 0; r < 16; ++r) {
          const int crow = 32 + (r & 3) + 8 * (r >> 2) + hi4;
          float p = exp2f(s1[r]);
          if (needM) {
            const int key = ks0 + crow;
            if (key > qme || key >= len) p = 0.f;
          }
          pr[r] = p; rsum += p;
        }
        unsigned int A0 = cvtpk_bf16(pr[0], pr[1]);
        unsigned int A1 = cvtpk_bf16(pr[2], pr[3]);
        unsigned int B0 = cvtpk_bf16(pr[4], pr[5]);
        unsigned int B1 = cvtpk_bf16(pr[6], pr[7]);
        asm volatile("v_permlane32_swap_b32 %0, %1" : "+v"(A0), "+v"(B0));
        asm volatile("v_permlane32_swap_b32 %0, %1" : "+v"(A1), "+v"(B1));
        pa[2].u[0] = A0; pa[2].u[1] = A1; pa[2].u[2] = B0; pa[2].u[3] = B1;
        unsigned int C0 = cvtpk_bf16(pr[8], pr[9]);
        unsigned int C1 = cvtpk_bf16(pr[10], pr[11]);
        unsigned int D0 = cvtpk_bf16(pr[12], pr[13]);
        unsigned int D1 = cvtpk_bf16(pr[14], pr[15]);
        asm volatile("v_permlane32_swap_b32 %0, %1" : "+v"(C0), "+v"(D0));
        asm volatile("v_permlane32_swap_b32 %0, %1" : "+v"(C1), "+v"(D1));
        pa[3].u[0] = C0; pa[3].u[1] = C1; pa[3].u[2] = D0; pa[3].u[3] = D1;
      }
      // ---- PV ----
#pragma unroll
      for (int dh = 0; dh < 2; ++dh) {
        const int vbase = (dh * 32 + l31) * 34 + hi4;
#pragma unroll
        for (int ks = 0; ks < 4; ++ks) {
          if (ks >= 2 && !dokb1) continue;
          uint2 va = *(const uint2*)&Vt[vbase + 8 * ks];
          uint2 vb2 = *(const uint2*)&Vt[vbase + 8 * ks + 2];
          pa_t vv;
          vv.u[0] = va.x; vv.u[1] = va.y; vv.u[2] = vb2.x; vv.u[3] = vb2.y;
          o[dh] = mfma32(pa[ks].s, vv.s, o[dh]);
        }
      }
    }
    my_kt = nxt; act = nact;
  }
#undef LDG

  rsum += __shfl_xor(rsum, 32, 64);

  float* mo = (float*)smem;                       // [64][66]
  __syncthreads();
  if (g == 1) {
#pragma unroll
    for (int r = 0; r < 16; ++r) {
      const int qb = wq * 32 + (r & 3) + 8 * (r >> 2) + hi4;
      mo[qb * 66 + l31]      = o[0][r];
      mo[qb * 66 + 32 + l31] = o[1][r];
    }
    if (hi == 0) lsh[1][wq * 32 + l31] = rsum;
  }
  __syncthreads();
  if (g == 0) {
    const float lt = rsum + lsh[1][wq * 32 + l31];
    const float inv = (lt > 0.f) ? (1.0f / lt) : 0.f;
    if (hi == 0) lsh[0][wq * 32 + l31] = inv;
#pragma unroll
    for (int r = 0; r < 16; ++r) {
      const int cr = (r & 3) + 8 * (r >> 2) + hi4;
      const int qb = wq * 32 + cr;
      const float iv = lsh[0][wq * 32 + cr];
      const int s = qt * 64 + qb;
      unsigned short* op =
          &attn_out[((size_t)(b * S_ + s)) * D_ + (bh & 15) * HD_ + l31];
      op[0]  = bf16_rne((o[0][r] + mo[qb * 66 + l31]) * iv);
      op[32] = bf16_rne((o[1][r] + mo[qb * 66 + 32 + l31]) * iv);
    }
  }
}

extern "C" void kernel_launch(void* const* d_in, const int* in_sizes, int n_in,
                              void* d_out, int out_size, void* d_ws, size_t ws_size,
                              hipStream_t stream) {
  const float* query = (const float*)d_in[0];
  const void*  mask  = d_in[1];
  const float* qkv_w = (const float*)d_in[2];
  const float* qkv_b = (const float*)d_in[3];
  const float* out_w = (const float*)d_in[4];
  const float* out_b = (const float*)d_in[5];
  float* out = (float*)d_out;

  char* ws = (char*)d_ws;
  unsigned short* qx     = (unsigned short*)(ws);                    // 0-8M
  unsigned short* wqkv   = (unsigned short*)(ws + (8u  << 20));      // 8-14M
  unsigned short* wout   = (unsigned short*)(ws + (14u << 20));      // 14-16M
  unsigned short* qbuf   = (unsigned short*)(ws + (16u << 20));      // 16-24M
  unsigned short* kbuf   = (unsigned short*)(ws + (24u << 20));      // 24-32M
  unsigned short* vbuf   = (unsigned short*)(ws + (32u << 20));      // 32-40M
  unsigned short* attn_o = qx;                                       // reuse 0-8M
  int* lens              = (int*)(ws + (40u << 20));

  const int na8 = B_ * S_ * D_ / 8, nb8 = 3 * D_ * D_ / 8, nc8 = D_ * D_ / 8;
  cvt3_kernel<<<(na8 + nb8 + nc8) / 256, 256, 0, stream>>>(
      query, qx, na8, qkv_w, wqkv, nb8, out_w, wout, nc8, mask, lens);

  gemm8p_kernel<<<192, 512, 0, stream>>>(qx, wqkv, D_, 3 * D_ / 256, qkv_b,
                                         qbuf, kbuf, vbuf);

  attn_kernel<<<1024, 256, 0, stream>>>(qbuf, kbuf, vbuf, lens, attn_o);

  dim3 g2(D_ / 128, B_ * S_ / 128);
  gemm_bt_kernel<<<g2, 256, 0, stream>>>(attn_o, wout, D_, D_, out_b, out);
}

// Round 19
// 131.984 us; speedup vs baseline: 1.1595x; 1.0494x over previous
//
#include <hip/hip_runtime.h>
#include <hip/hip_bf16.h>
#include <stdint.h>

#define S_  2048
#define B_  2
#define H_  16
#define D_  1024
#define HD_ 64

typedef short short8 __attribute__((ext_vector_type(8)));
typedef float f32x4  __attribute__((ext_vector_type(4)));
typedef float f32x16 __attribute__((ext_vector_type(16)));

__device__ __forceinline__ unsigned short bf16_rne(float f) {
  unsigned int u = __float_as_uint(f);
  u += 0x7fffu + ((u >> 16) & 1u);
  return (unsigned short)(u >> 16);
}

__device__ __forceinline__ f32x4 mfma_bf16(short8 a, short8 b, f32x4 c) {
  return __builtin_amdgcn_mfma_f32_16x16x32_bf16(a, b, c, 0, 0, 0);
}

__device__ __forceinline__ f32x16 mfma32(short8 a, short8 b, f32x16 c) {
  return __builtin_amdgcn_mfma_f32_32x32x16_bf16(a, b, c, 0, 0, 0);
}

__device__ __forceinline__ unsigned int cvtpk_bf16(float lo, float hi) {
  unsigned int r;
  asm("v_cvt_pk_bf16_f32 %0, %1, %2" : "=v"(r) : "v"(lo), "v"(hi));
  return r;
}

// ---------------- fused f32 -> bf16 for 3 tensors + lengths scan ----------
__global__ void cvt3_kernel(const float* __restrict__ a, unsigned short* __restrict__ oa, int na8,
                            const float* __restrict__ b, unsigned short* __restrict__ ob, int nb8,
                            const float* __restrict__ c, unsigned short* __restrict__ oc, int nc8,
                            const void* __restrict__ mask, int* __restrict__ lens) {
  if (blockIdx.x == 0) {
    __shared__ int mn[B_];
    __shared__ int anyb;
    int tt = threadIdx.x;
    if (tt < B_) mn[tt] = S_;
    if (tt == 0) anyb = 0;
    __syncthreads();
    const unsigned char* mb = (const unsigned char*)mask;
    for (int i = tt; i < B_ * S_; i += 256) {
      if (mb[i]) { anyb = 1; atomicMin(&mn[i >> 11], i & (S_ - 1)); }
    }
    __syncthreads();
    if (!anyb) {
      const int* mi = (const int*)mask;
      for (int i = tt; i < B_ * S_; i += 256) {
        if (mi[i]) atomicMin(&mn[i >> 11], i & (S_ - 1));
      }
      __syncthreads();
    }
    if (tt < B_) lens[tt] = mn[tt];
  }
  int i = blockIdx.x * blockDim.x + threadIdx.x;
  const float* in; unsigned short* out; int idx;
  if (i < na8) { in = a; out = oa; idx = i; }
  else if (i < na8 + nb8) { in = b; out = ob; idx = i - na8; }
  else if (i < na8 + nb8 + nc8) { in = c; out = oc; idx = i - na8 - nb8; }
  else return;
  const float4* p = (const float4*)in + (size_t)idx * 2;
  float4 x = p[0], y = p[1];
  union { unsigned short u[8]; short8 v; } r;
  r.u[0] = bf16_rne(x.x); r.u[1] = bf16_rne(x.y);
  r.u[2] = bf16_rne(x.z); r.u[3] = bf16_rne(x.w);
  r.u[4] = bf16_rne(y.x); r.u[5] = bf16_rne(y.y);
  r.u[6] = bf16_rne(y.z); r.u[7] = bf16_rne(y.w);
  *((short8*)out + idx) = r.v;
}

// ---------------- 256x256 8-phase bf16 GEMM (QKV, scatter epilogue) --------
// Q scaled by 0.125 (natural-exp softmax via __expf); K, V to [bh][s][64].
__global__ __launch_bounds__(512, 2) void gemm8p_kernel(
    const unsigned short* __restrict__ A,
    const unsigned short* __restrict__ W,
    int K, int NBX,
    const float* __restrict__ bias,
    unsigned short* __restrict__ qb,
    unsigned short* __restrict__ kb,
    unsigned short* __restrict__ vb) {
  __shared__ __align__(16) unsigned short lds[65536];   // 128 KB

  const int nwg = gridDim.x;
  const int cpx = nwg >> 3;
  const int bid = blockIdx.x;
  const int virt = (bid & 7) * cpx + (bid >> 3);
  const int bx = virt % NBX, by = virt / NBX;
  const int tile_m = by * 256, tile_n = bx * 256;
  const int t = threadIdx.x;
  const int lane = t & 63, w = t >> 6;
  const int wm = w >> 2, wn = w & 3;
  const int l15 = lane & 15, lk = lane >> 4;
  const int NT = K >> 6;

  f32x4 acc[8][4];
#pragma unroll
  for (int i = 0; i < 8; i++)
#pragma unroll
    for (int j = 0; j < 4; j++) { f32x4 z = {0.f, 0.f, 0.f, 0.f}; acc[i][j] = z; }

  const int L0 = t, L1 = 512 + t;
  const int r0 = L0 >> 3, c0 = (L0 & 7) ^ (r0 & 7);
  const int r1 = L1 >> 3, c1 = (L1 & 7) ^ (r1 & 7);

#define STAGE_HALF(SRC, GROW0, DSTE, KC)                                      \
  {                                                                           \
    __builtin_amdgcn_global_load_lds(                                         \
        (const __attribute__((address_space(1))) void*)(                      \
            (SRC) + (size_t)((GROW0) + r0) * K + (KC) + c0 * 8),              \
        (__attribute__((address_space(3))) void*)(&lds[(DSTE) + L0 * 8]),     \
        16, 0, 0);                                                            \
    __builtin_amdgcn_global_load_lds(                                         \
        (const __attribute__((address_space(1))) void*)(                      \
            (SRC) + (size_t)((GROW0) + r1) * K + (KC) + c1 * 8),              \
        (__attribute__((address_space(3))) void*)(&lds[(DSTE) + L1 * 8]),     \
        16, 0, 0);                                                            \
  }

  STAGE_HALF(A, tile_m,        0,    0);
  STAGE_HALF(W, tile_n,        32768, 0);
  STAGE_HALF(A, tile_m + 128,  8192, 0);
  STAGE_HALF(W, tile_n + 128,  32768 + 8192, 0);
  asm volatile("s_waitcnt vmcnt(4)" ::: "memory");
  __builtin_amdgcn_s_barrier();

  for (int tc = 0; tc < NT; ++tc) {
    const int cb = (tc & 1) * 16384;
    const int ob = ((tc & 1) ^ 1) * 16384;
    int tn = tc + 1; if (tn >= NT) tn = NT - 1;
    const int k0n = tn << 6;

#pragma unroll
    for (int p = 0; p < 4; ++p) {
      const int mh = (p & 1);
      const int nh = (p >> 1);
      short8 af[4][2], bfr[2][2];
#pragma unroll
      for (int fi = 0; fi < 4; ++fi) {
        const int rl = fi * 32 + wm * 16 + l15;
#pragma unroll
        for (int ks = 0; ks < 2; ++ks) {
          const int sw = (ks * 4 + lk) ^ (rl & 7);
          af[fi][ks] = *(const short8*)&lds[cb + mh * 8192 + rl * 64 + sw * 8];
        }
      }
#pragma unroll
      for (int fj = 0; fj < 2; ++fj) {
        const int cl = wn * 32 + fj * 16 + l15;
#pragma unroll
        for (int ks = 0; ks < 2; ++ks) {
          const int sw = (ks * 4 + lk) ^ (cl & 7);
          bfr[fj][ks] =
              *(const short8*)&lds[32768 + cb + nh * 8192 + cl * 64 + sw * 8];
        }
      }
      if (p == 0)      STAGE_HALF(A, tile_m,       ob,                k0n)
      else if (p == 1) STAGE_HALF(W, tile_n,       32768 + ob,        k0n)
      else if (p == 2) STAGE_HALF(A, tile_m + 128, ob + 8192,         k0n)
      else             STAGE_HALF(W, tile_n + 128, 32768 + ob + 8192, k0n);
      if (p != 2) asm volatile("s_waitcnt vmcnt(4)" ::: "memory");
      else        asm volatile("" ::: "memory");
      __builtin_amdgcn_s_barrier();
      asm volatile("s_waitcnt lgkmcnt(0)" ::: "memory");
      __builtin_amdgcn_s_setprio(1);
#pragma unroll
      for (int fi = 0; fi < 4; ++fi)
#pragma unroll
        for (int fj = 0; fj < 2; ++fj)
#pragma unroll
          for (int ks = 0; ks < 2; ++ks)
            acc[mh * 4 + fi][nh * 2 + fj] =
                mfma_bf16(af[fi][ks], bfr[fj][ks], acc[mh * 4 + fi][nh * 2 + fj]);
      __builtin_amdgcn_s_setprio(0);
      __builtin_amdgcn_s_barrier();
    }
  }
  asm volatile("s_waitcnt vmcnt(0)" ::: "memory");
#undef STAGE_HALF

#pragma unroll
  for (int j = 0; j < 4; ++j) {
    const int gn = tile_n + (j >> 1) * 128 + wn * 32 + (j & 1) * 16 + l15;
    const float bv = bias[gn];
    const int which = gn >> 10, dd = gn & (D_ - 1);
    const int h = dd >> 6, d = dd & 63;
    unsigned short* dstp = (which == 0) ? qb : (which == 1) ? kb : vb;
    const float mul = (which == 0) ? 0.125f : 1.0f;
#pragma unroll
    for (int i = 0; i < 8; ++i) {
      const int gmb = tile_m + (i >> 2) * 128 + (i & 3) * 32 + wm * 16 + lk * 4;
#pragma unroll
      for (int r = 0; r < 4; ++r) {
        const int gm = gmb + r;
        const int bb = gm >> 11, s = gm & (S_ - 1);
        dstp[((size_t)((bb * H_ + h) * S_ + s)) * HD_ + d] =
            bf16_rne((acc[i][j][r] + bv) * mul);
      }
    }
  }
}

// ---------------- 128x128 bf16 GEMM, 2-phase dbuf, C = A*W^T + bias -------
__global__ __launch_bounds__(256) void gemm_bt_kernel(
    const unsigned short* __restrict__ A,
    const unsigned short* __restrict__ W,
    int K, int N,
    const float* __restrict__ bias,
    float* __restrict__ outf) {
  __shared__ unsigned short As[2][128 * 32];
  __shared__ unsigned short Bs[2][128 * 32];
  const int tile_m = blockIdx.y * 128;
  const int tile_n = blockIdx.x * 128;
  const int t = threadIdx.x;
  const int lane = t & 63;
  const int w = t >> 6;
  const int wr = w >> 1, wc = w & 1;
  const int l15 = lane & 15, lk = lane >> 4;
  const int NT = K >> 5;

  f32x4 acc[4][4];
#pragma unroll
  for (int i = 0; i < 4; i++)
#pragma unroll
    for (int j = 0; j < 4; j++) { f32x4 z = {0.f, 0.f, 0.f, 0.f}; acc[i][j] = z; }

#define STAGE_BT(BUF, KC)                                                     \
  {                                                                           \
    _Pragma("unroll")                                                         \
    for (int c = 0; c < 2; ++c) {                                             \
      int e = (c * 256 + t) * 8;                                              \
      int row = e >> 5, col = e & 31;                                         \
      __builtin_amdgcn_global_load_lds(                                       \
          (const __attribute__((address_space(1))) void*)(                    \
              A + (size_t)(tile_m + row) * K + (KC) + col),                   \
          (__attribute__((address_space(3))) void*)(&As[BUF][e]), 16, 0, 0);  \
      __builtin_amdgcn_global_load_lds(                                       \
          (const __attribute__((address_space(1))) void*)(                    \
              W + (size_t)(tile_n + row) * K + (KC) + col),                   \
          (__attribute__((address_space(3))) void*)(&Bs[BUF][e]), 16, 0, 0);  \
    }                                                                         \
  }

  STAGE_BT(0, 0);
  asm volatile("s_waitcnt vmcnt(0)" ::: "memory");
  __syncthreads();

  int cur = 0;
  for (int tc = 0; tc < NT; ++tc) {
    if (tc + 1 < NT) STAGE_BT(cur ^ 1, (tc + 1) << 5);

    const unsigned short* Ac = As[cur];
    const unsigned short* Bc = Bs[cur];
    short8 af[4], bfr[4];
#pragma unroll
    for (int i = 0; i < 4; i++)
      af[i] = *(const short8*)&Ac[(wr * 64 + i * 16 + l15) * 32 + lk * 8];
#pragma unroll
    for (int j = 0; j < 4; j++)
      bfr[j] = *(const short8*)&Bc[(wc * 64 + j * 16 + l15) * 32 + lk * 8];
    __builtin_amdgcn_s_setprio(1);
#pragma unroll
    for (int i = 0; i < 4; i++)
#pragma unroll
      for (int j = 0; j < 4; j++)
        acc[i][j] = mfma_bf16(af[i], bfr[j], acc[i][j]);
    __builtin_amdgcn_s_setprio(0);

    asm volatile("s_waitcnt vmcnt(0)" ::: "memory");
    __syncthreads();
    cur ^= 1;
  }
#undef STAGE_BT

#pragma unroll
  for (int i = 0; i < 4; i++) {
#pragma unroll
    for (int j = 0; j < 4; j++) {
      int gn = tile_n + wc * 64 + j * 16 + l15;
      float bv = bias[gn];
#pragma unroll
      for (int r = 0; r < 4; r++) {
        int gm = tile_m + wr * 64 + i * 16 + lk * 4 + r;
        outf[(size_t)gm * N + gn] = acc[i][j][r] + bv;
      }
    }
  }
}

// ---------------- flash attention: 32x32 MFMA, in-register softmax ---------
// R13-verified kernel VERBATIM (attn 56us): 2-way split-K, balanced CU
// mapping, __expf softmax (native v_exp path; Q pre-scaled 0.125).
__global__ __launch_bounds__(256, 3) void attn_kernel(
    const unsigned short* __restrict__ qbuf,
    const unsigned short* __restrict__ kbuf,
    const unsigned short* __restrict__ vbuf,
    const int* __restrict__ lens,
    unsigned short* __restrict__ attn_out) {
  __shared__ __align__(16) char smem[33792];
  __shared__ float lsh[2][64];
  // Ks[g] u16[64][64] XOR-swz @ g*8192 ; Vt[g] u32[64][34] @ 16384+g*8704
  // epilogue overlay: mo f32[64][66] @ 0

  const int bid = blockIdx.x;
  const int xcd = bid & 7, nn = bid >> 3;
  const int rr = nn >> 5, cc = nn & 31;
  const int bh = (xcd << 2) | (cc & 3);
  const int qlo = cc >> 2;
  const int qt = (rr & 1) ? (8 * rr + 7 - qlo) : (8 * rr + qlo);
  const int b = bh >> 4;
  const int len = lens[b];
  const int t = threadIdx.x;
  const int lane = t & 63, w = t >> 6;
  const int g = w >> 1, wq = w & 1;
  const int l31 = lane & 31, hi = lane >> 5;
  const int hi8 = hi * 8, hi4 = hi * 4;
  const int q0 = qt * 64 + wq * 32;
  const int qme = q0 + l31;

  unsigned short* Ks = (unsigned short*)(smem + g * 8192);
  unsigned int*   Vt = (unsigned int*)(smem + 16384 + g * 8704);

  const unsigned short* qbh = qbuf + (size_t)bh * S_ * HD_;
  const unsigned short* kbh = kbuf + (size_t)bh * S_ * HD_;
  const unsigned short* vbh = vbuf + (size_t)bh * S_ * HD_;

  short8 qf[4];
#pragma unroll
  for (int ds = 0; ds < 4; ++ds)
    qf[ds] = *(const short8*)&qbh[(size_t)(q0 + l31) * HD_ + ds * 16 + hi8];

  f32x16 o[2] = {{}, {}};
  float rsum = 0.f;

  const int ke = (len - 1) >> 6;
  const int kt_end = qt < ke ? qt : ke;
  const int NI = (kt_end >> 1) + 1;

  // staging decomposition within a 128-thread group
  const int tg = t & 127;
  const int kr0 = tg >> 3, kc0 = tg & 7;        // K: 4 rows kr0+16m
  const int vr2 = tg & 31, vcb = (tg >> 5) << 1; // V: key-pair, 2 d-groups

  short8 pk[4], pva0 = {}, pva1 = {}, pvb0 = {}, pvb1 = {};
#pragma unroll
  for (int m = 0; m < 4; ++m) pk[m] = pva0;

#define LDG(KT)                                                               \
  {                                                                           \
    int ks_ = (KT) * 64;                                                      \
    pk[0] = *(const short8*)&kbh[(size_t)(ks_ + kr0     ) * HD_ + kc0 * 8];   \
    pk[1] = *(const short8*)&kbh[(size_t)(ks_ + kr0 + 16) * HD_ + kc0 * 8];   \
    pk[2] = *(const short8*)&kbh[(size_t)(ks_ + kr0 + 32) * HD_ + kc0 * 8];   \
    pk[3] = *(const short8*)&kbh[(size_t)(ks_ + kr0 + 48) * HD_ + kc0 * 8];   \
    const unsigned short* vp = vbh + (size_t)(ks_ + 2 * vr2) * HD_ + vcb * 8; \
    pva0 = *(const short8*)vp;       pva1 = *(const short8*)(vp + HD_);       \
    pvb0 = *(const short8*)(vp + 8); pvb1 = *(const short8*)(vp + HD_ + 8);   \
  }

  int my_kt = g;
  bool act = (my_kt <= kt_end);
  if (act) LDG(my_kt);

  typedef union { unsigned int u[4]; short8 s; } pa_t;

  for (int i = 0; i < NI; ++i) {
    __syncthreads();
    if (act) {
#pragma unroll
      for (int m = 0; m < 4; ++m) {
        const int r = kr0 + 16 * m;
        *(short8*)&Ks[r * 64 + ((kc0 ^ (r & 7)) << 3)] = pk[m];
      }
#pragma unroll
      for (int j = 0; j < 8; ++j) {
        unsigned int w0 = (unsigned int)(unsigned short)pva0[j] |
                          ((unsigned int)(unsigned short)pva1[j] << 16);
        unsigned int w1 = (unsigned int)(unsigned short)pvb0[j] |
                          ((unsigned int)(unsigned short)pvb1[j] << 16);
        Vt[(vcb * 8 + j) * 34 + vr2] = w0;
        Vt[((vcb + 1) * 8 + j) * 34 + vr2] = w1;
      }
    }
    __syncthreads();
    const int nxt = my_kt + 2;
    const bool nact = (nxt <= kt_end);
    if (nact) LDG(nxt);

    const int ks0 = my_kt * 64;
    if (act && ks0 <= q0 + 31) {
      // mask needed iff tile touches the diagonal (last key >= first q-row)
      // or the padding boundary. NOTE: >= q0, not > q0+31 (wq=1 diag tile!)
      const bool needM = (ks0 + 63 >= q0) || (ks0 + 63 >= len);
      const bool dokb1 = (ks0 + 32 <= q0 + 31) && (ks0 + 32 < len);

      pa_t pa[4];
      // ---- kb = 0 ----
      {
        f32x16 s0 = {};
#pragma unroll
        for (int ds = 0; ds < 4; ++ds) {
          const int cg = ((ds << 1) | hi) ^ (l31 & 7);
          const short8 kf = *(const short8*)&Ks[l31 * 64 + (cg << 3)];
          s0 = mfma32(kf, qf[ds], s0);
        }
        float pr[16];
#pragma unroll
        for (int r = 0; r < 16; ++r) {
          const int crow = (r & 3) + 8 * (r >> 2) + hi4;
          float p = __expf(s0[r]);
          if (needM) {
            const int key = ks0 + crow;
            if (key > qme || key >= len) p = 0.f;
          }
          pr[r] = p; rsum += p;
        }
        unsigned int A0 = cvtpk_bf16(pr[0], pr[1]);
        unsigned int A1 = cvtpk_bf16(pr[2], pr[3]);
        unsigned int B0 = cvtpk_bf16(pr[4], pr[5]);
        unsigned int B1 = cvtpk_bf16(pr[6], pr[7]);
        asm volatile("v_permlane32_swap_b32 %0, %1" : "+v"(A0), "+v"(B0));
        asm volatile("v_permlane32_swap_b32 %0, %1" : "+v"(A1), "+v"(B1));
        pa[0].u[0] = A0; pa[0].u[1] = A1; pa[0].u[2] = B0; pa[0].u[3] = B1;
        unsigned int C0 = cvtpk_bf16(pr[8], pr[9]);
        unsigned int C1 = cvtpk_bf16(pr[10], pr[11]);
        unsigned int D0 = cvtpk_bf16(pr[12], pr[13]);
        unsigned int D1 = cvtpk_bf16(pr[14], pr[15]);
        asm volatile("v_permlane32_swap_b32 %0, %1" : "+v"(C0), "+v"(D0));
        asm volatile("v_permlane32_swap_b32 %0, %1" : "+v"(C1), "+v"(D1));
        pa[1].u[0] = C0; pa[1].u[1] = C1; pa[1].u[2] = D0; pa[1].u[3] = D1;
      }
      // ---- kb = 1 ----
      if (dokb1) {
        f32x16 s1 = {};
#pragma unroll
        for (int ds = 0; ds < 4; ++ds) {
          const int cg = ((ds << 1) | hi) ^ (l31 & 7);
          const short8 kf = *(const short8*)&Ks[(32 + l31) * 64 + (cg << 3)];
          s1 = mfma32(kf, qf[ds], s1);
        }
        float pr[16];
#pragma unroll
        for (int r = 0; r < 16; ++r) {
          const int crow = 32 + (r & 3) + 8 * (r >> 2) + hi4;
          float p = __expf(s1[r]);
          if (needM) {
            const int key = ks0 + crow;
            if (key > qme || key >= len) p = 0.f;
          }
          pr[r] = p; rsum += p;
        }
        unsigned int A0 = cvtpk_bf16(pr[0], pr[1]);
        unsigned int A1 = cvtpk_bf16(pr[2], pr[3]);
        unsigned int B0 = cvtpk_bf16(pr[4], pr[5]);
        unsigned int B1 = cvtpk_bf16(pr[6], pr[7]);
        asm volatile("v_permlane32_swap_b32 %0, %1" : "+v"(A0), "+v"(B0));
        asm volatile("v_permlane32_swap_b32 %0, %1" : "+v"(A1), "+v"(B1));
        pa[2].u[0] = A0; pa[2].u[1] = A1; pa[2].u[2] = B0; pa[2].u[3] = B1;
        unsigned int C0 = cvtpk_bf16(pr[8], pr[9]);
        unsigned int C1 = cvtpk_bf16(pr[10], pr[11]);
        unsigned int D0 = cvtpk_bf16(pr[12], pr[13]);
        unsigned int D1 = cvtpk_bf16(pr[14], pr[15]);
        asm volatile("v_permlane32_swap_b32 %0, %1" : "+v"(C0), "+v"(D0));
        asm volatile("v_permlane32_swap_b32 %0, %1" : "+v"(C1), "+v"(D1));
        pa[3].u[0] = C0; pa[3].u[1] = C1; pa[3].u[2] = D0; pa[3].u[3] = D1;
      }
      // ---- PV ----
#pragma unroll
      for (int dh = 0; dh < 2; ++dh) {
        const int vbase = (dh * 32 + l31) * 34 + hi4;
#pragma unroll
        for (int ks = 0; ks < 4; ++ks) {
          if (ks >= 2 && !dokb1) continue;
          uint2 va = *(const uint2*)&Vt[vbase + 8 * ks];
          uint2 vb2 = *(const uint2*)&Vt[vbase + 8 * ks + 2];
          pa_t vv;
          vv.u[0] = va.x; vv.u[1] = va.y; vv.u[2] = vb2.x; vv.u[3] = vb2.y;
          o[dh] = mfma32(pa[ks].s, vv.s, o[dh]);
        }
      }
    }
    my_kt = nxt; act = nact;
  }
#undef LDG

  rsum += __shfl_xor(rsum, 32, 64);

  float* mo = (float*)smem;                       // [64][66]
  __syncthreads();
  if (g == 1) {
#pragma unroll
    for (int r = 0; r < 16; ++r) {
      const int qb = wq * 32 + (r & 3) + 8 * (r >> 2) + hi4;
      mo[qb * 66 + l31]      = o[0][r];
      mo[qb * 66 + 32 + l31] = o[1][r];
    }
    if (hi == 0) lsh[1][wq * 32 + l31] = rsum;
  }
  __syncthreads();
  if (g == 0) {
    const float lt = rsum + lsh[1][wq * 32 + l31];
    const float inv = (lt > 0.f) ? (1.0f / lt) : 0.f;
    if (hi == 0) lsh[0][wq * 32 + l31] = inv;
#pragma unroll
    for (int r = 0; r < 16; ++r) {
      const int cr = (r & 3) + 8 * (r >> 2) + hi4;
      const int qb = wq * 32 + cr;
      const float iv = lsh[0][wq * 32 + cr];
      const int s = qt * 64 + qb;
      unsigned short* op =
          &attn_out[((size_t)(b * S_ + s)) * D_ + (bh & 15) * HD_ + l31];
      op[0]  = bf16_rne((o[0][r] + mo[qb * 66 + l31]) * iv);
      op[32] = bf16_rne((o[1][r] + mo[qb * 66 + 32 + l31]) * iv);
    }
  }
}

extern "C" void kernel_launch(void* const* d_in, const int* in_sizes, int n_in,
                              void* d_out, int out_size, void* d_ws, size_t ws_size,
                              hipStream_t stream) {
  const float* query = (const float*)d_in[0];
  const void*  mask  = d_in[1];
  const float* qkv_w = (const float*)d_in[2];
  const float* qkv_b = (const float*)d_in[3];
  const float* out_w = (const float*)d_in[4];
  const float* out_b = (const float*)d_in[5];
  float* out = (float*)d_out;

  char* ws = (char*)d_ws;
  unsigned short* qx     = (unsigned short*)(ws);                    // 0-8M
  unsigned short* wqkv   = (unsigned short*)(ws + (8u  << 20));      // 8-14M
  unsigned short* wout   = (unsigned short*)(ws + (14u << 20));      // 14-16M
  unsigned short* qbuf   = (unsigned short*)(ws + (16u << 20));      // 16-24M
  unsigned short* kbuf   = (unsigned short*)(ws + (24u << 20));      // 24-32M
  unsigned short* vbuf   = (unsigned short*)(ws + (32u << 20));      // 32-40M
  unsigned short* attn_o = qx;                                       // reuse 0-8M
  int* lens              = (int*)(ws + (40u << 20));

  const int na8 = B_ * S_ * D_ / 8, nb8 = 3 * D_ * D_ / 8, nc8 = D_ * D_ / 8;
  cvt3_kernel<<<(na8 + nb8 + nc8) / 256, 256, 0, stream>>>(
      query, qx, na8, qkv_w, wqkv, nb8, out_w, wout, nc8, mask, lens);

  gemm8p_kernel<<<192, 512, 0, stream>>>(qx, wqkv, D_, 3 * D_ / 256, qkv_b,
                                         qbuf, kbuf, vbuf);

  attn_kernel<<<1024, 256, 0, stream>>>(qbuf, kbuf, vbuf, lens, attn_o);

  dim3 g2(D_ / 128, B_ * S_ / 128);
  gemm_bt_kernel<<<g2, 256, 0, stream>>>(attn_o, wout, D_, D_, out_b, out);
}